// Round 5
// baseline (1380.520 us; speedup 1.0000x reference)
//
#include <hip/hip_runtime.h>
#include <math.h>

#define SCAN_BLK 256

// ---------------- CSR build ----------------
__global__ void count_kernel(const int* __restrict__ ei, int* __restrict__ deg, int E) {
    int e = blockIdx.x * blockDim.x + threadIdx.x;
    if (e < E) atomicAdd(&deg[ei[E + e]], 1);
}

__global__ void scan1_kernel(const int* __restrict__ deg, int* __restrict__ part,
                             int* __restrict__ bsum, int N) {
    __shared__ int sm[SCAN_BLK];
    int i = blockIdx.x * SCAN_BLK + threadIdx.x;
    int v = (i < N) ? deg[i] : 0;
    sm[threadIdx.x] = v;
    __syncthreads();
    for (int off = 1; off < SCAN_BLK; off <<= 1) {
        int t = (threadIdx.x >= off) ? sm[threadIdx.x - off] : 0;
        __syncthreads();
        sm[threadIdx.x] += t;
        __syncthreads();
    }
    if (i < N) part[i] = sm[threadIdx.x] - v;
    if (threadIdx.x == SCAN_BLK - 1) bsum[blockIdx.x] = sm[threadIdx.x];
}

__global__ void scan2_kernel(const int* __restrict__ bsum, int* __restrict__ boff, int nb) {
    __shared__ int sm[512];
    int v = (threadIdx.x < nb) ? bsum[threadIdx.x] : 0;
    sm[threadIdx.x] = v;
    __syncthreads();
    for (int off = 1; off < 512; off <<= 1) {
        int t = (threadIdx.x >= off) ? sm[threadIdx.x - off] : 0;
        __syncthreads();
        sm[threadIdx.x] += t;
        __syncthreads();
    }
    if (threadIdx.x < nb) boff[threadIdx.x] = sm[threadIdx.x] - v;
}

__global__ void scan3_kernel(int* __restrict__ rowptr, const int* __restrict__ boff,
                             int N, int E) {
    int i = blockIdx.x * blockDim.x + threadIdx.x;
    if (i < N) rowptr[i] += boff[i / SCAN_BLK];
    if (i == 0) rowptr[N] = E;
}

// scatter PERM: srcp[idx]=src, eap[idx*8..] = ea row (CSR-ordered attrs)
__global__ void scatterP_kernel(const int* __restrict__ ei, const int* __restrict__ rowptr,
                                int* __restrict__ cursor, int* __restrict__ srcp,
                                float* __restrict__ eap, const float* __restrict__ ea, int E) {
    int e = blockIdx.x * blockDim.x + threadIdx.x;
    if (e >= E) return;
    int dst = ei[E + e];
    int pos = atomicAdd(&cursor[dst], 1);
    int idx = rowptr[dst] + pos;
    srcp[idx] = ei[e];
    float4 a0 = *(const float4*)(ea + (size_t)e * 8);
    float4 a1 = *(const float4*)(ea + (size_t)e * 8 + 4);
    *(float4*)(eap + (size_t)idx * 8)     = a0;
    *(float4*)(eap + (size_t)idx * 8 + 4) = a1;
}

// scatter fallback: rec[idx] = (src, eid)
__global__ void scatterR_kernel(const int* __restrict__ ei, const int* __restrict__ rowptr,
                                int* __restrict__ cursor, int2* __restrict__ rec, int E) {
    int e = blockIdx.x * blockDim.x + threadIdx.x;
    if (e >= E) return;
    int dst = ei[E + e];
    int pos = atomicAdd(&cursor[dst], 1);
    rec[rowptr[dst] + pos] = make_int2(ei[e], e);
}

// ------- node projections: Q,K,V (head-padded layout), S (unpadded) -------
template<int CIN, int H, int C, int CP>
__global__ void proj_kernel(const float* __restrict__ X,
                            const float* __restrict__ wq, const float* __restrict__ bq,
                            const float* __restrict__ wk, const float* __restrict__ bk,
                            const float* __restrict__ wv, const float* __restrict__ bv,
                            const float* __restrict__ wsk, const float* __restrict__ bsk,
                            float* __restrict__ Q, float* __restrict__ K,
                            float* __restrict__ V, float* __restrict__ S, int N)
{
    const int HC = H * C;
    int idx = blockIdx.x * blockDim.x + threadIdx.x;
    if (idx >= N * HC) return;
    int n = idx / HC;
    int c = idx - n * HC;
    int h = c / C;
    int cc = c - h * C;
    float q = bq[c], k = bk[c], v = bv[c], s = bsk[c];
    const float* xr = X + (size_t)n * CIN;
#pragma unroll
    for (int i = 0; i < CIN; ++i) {
        float xi = xr[i];
        q = fmaf(xi, wq[i * HC + c], q);
        k = fmaf(xi, wk[i * HC + c], k);
        v = fmaf(xi, wv[i * HC + c], v);
        s = fmaf(xi, wsk[i * HC + c], s);
    }
    size_t po = (size_t)n * (H * CP) + h * CP + cc;
    Q[po] = q; K[po] = k; V[po] = v;
    S[(size_t)n * HC + c] = s;
}

// ---- fused gather+gate, H=8: thread per (node, head), factorized e -----
template<int C, int CP, bool PERM>
__global__ void gather8f_kernel(const int* __restrict__ rowptr,
                                const int* __restrict__ srcp,
                                const int2* __restrict__ rec,
                                const float* __restrict__ eap,
                                const float* __restrict__ ea,
                                const float* __restrict__ we,
                                const float* __restrict__ Q,
                                const float* __restrict__ K,
                                const float* __restrict__ V,
                                const float* __restrict__ S,
                                const float* __restrict__ wb,
                                float* __restrict__ OUT,
                                int N, float scale)
{
    const int HC = 8 * C;
    const int HCP = 8 * CP;
    int tid = blockIdx.x * blockDim.x + threadIdx.x;
    int n = tid >> 3;
    int h = tid & 7;
    if (n >= N) return;

    float q[C];
    const float* Qp = Q + (size_t)n * HCP + h * CP;
#pragma unroll
    for (int c = 0; c < C; ++c) q[c] = Qp[c];

    float qe[8];
#pragma unroll
    for (int d = 0; d < 8; ++d) {
        float t = 0.f;
#pragma unroll
        for (int c = 0; c < C; ++c) t = fmaf(we[d * HC + h * C + c], q[c], t);
        qe[d] = t;
    }

    float num[C];
#pragma unroll
    for (int c = 0; c < C; ++c) num[c] = 0.f;
    float sacc[8];
#pragma unroll
    for (int d = 0; d < 8; ++d) sacc[d] = 0.f;
    float den = 0.f;

    int rs = rowptr[n], re = rowptr[n + 1];
    int j = rs;
    for (; j + 1 < re; j += 2) {
        int s0, s1;
        const float *A0, *A1;
        if (PERM) {
            s0 = srcp[j]; s1 = srcp[j + 1];
            A0 = eap + (size_t)j * 8; A1 = eap + (size_t)(j + 1) * 8;
        } else {
            int2 r0 = rec[j], r1 = rec[j + 1];
            s0 = r0.x; s1 = r1.x;
            A0 = ea + (size_t)r0.y * 8; A1 = ea + (size_t)r1.y * 8;
        }
        float4 a00 = *(const float4*)A0;
        float4 a01 = *(const float4*)(A0 + 4);
        float4 a10 = *(const float4*)A1;
        float4 a11 = *(const float4*)(A1 + 4);
        const float* K0 = K + (size_t)s0 * HCP + h * CP;
        const float* V0 = V + (size_t)s0 * HCP + h * CP;
        const float* K1 = K + (size_t)s1 * HCP + h * CP;
        const float* V1 = V + (size_t)s1 * HCP + h * CP;
        float k0[CP], v0[CP], k1[CP], v1[CP];
#pragma unroll
        for (int t4 = 0; t4 < CP / 4; ++t4) {
            *(float4*)(k0 + 4 * t4) = *(const float4*)(K0 + 4 * t4);
            *(float4*)(v0 + 4 * t4) = *(const float4*)(V0 + 4 * t4);
            *(float4*)(k1 + 4 * t4) = *(const float4*)(K1 + 4 * t4);
            *(float4*)(v1 + 4 * t4) = *(const float4*)(V1 + 4 * t4);
        }
        float d0 = 0.f, d1 = 0.f;
#pragma unroll
        for (int c = 0; c < C; ++c) {
            d0 = fmaf(q[c], k0[c], d0);
            d1 = fmaf(q[c], k1[c], d1);
        }
        float qa0 = qe[0] * a00.x;
        qa0 = fmaf(qe[1], a00.y, qa0); qa0 = fmaf(qe[2], a00.z, qa0);
        qa0 = fmaf(qe[3], a00.w, qa0); qa0 = fmaf(qe[4], a01.x, qa0);
        qa0 = fmaf(qe[5], a01.y, qa0); qa0 = fmaf(qe[6], a01.z, qa0);
        qa0 = fmaf(qe[7], a01.w, qa0);
        float qa1 = qe[0] * a10.x;
        qa1 = fmaf(qe[1], a10.y, qa1); qa1 = fmaf(qe[2], a10.z, qa1);
        qa1 = fmaf(qe[3], a10.w, qa1); qa1 = fmaf(qe[4], a11.x, qa1);
        qa1 = fmaf(qe[5], a11.y, qa1); qa1 = fmaf(qe[6], a11.z, qa1);
        qa1 = fmaf(qe[7], a11.w, qa1);
        float ex0 = __expf((d0 + qa0) * scale);
        float ex1 = __expf((d1 + qa1) * scale);
        den += ex0 + ex1;
#pragma unroll
        for (int c = 0; c < C; ++c) {
            num[c] = fmaf(ex0, v0[c], num[c]);
            num[c] = fmaf(ex1, v1[c], num[c]);
        }
        sacc[0] = fmaf(ex0, a00.x, fmaf(ex1, a10.x, sacc[0]));
        sacc[1] = fmaf(ex0, a00.y, fmaf(ex1, a10.y, sacc[1]));
        sacc[2] = fmaf(ex0, a00.z, fmaf(ex1, a10.z, sacc[2]));
        sacc[3] = fmaf(ex0, a00.w, fmaf(ex1, a10.w, sacc[3]));
        sacc[4] = fmaf(ex0, a01.x, fmaf(ex1, a11.x, sacc[4]));
        sacc[5] = fmaf(ex0, a01.y, fmaf(ex1, a11.y, sacc[5]));
        sacc[6] = fmaf(ex0, a01.z, fmaf(ex1, a11.z, sacc[6]));
        sacc[7] = fmaf(ex0, a01.w, fmaf(ex1, a11.w, sacc[7]));
    }
    if (j < re) {
        int s0;
        const float* A0;
        if (PERM) {
            s0 = srcp[j];
            A0 = eap + (size_t)j * 8;
        } else {
            int2 r0 = rec[j];
            s0 = r0.x;
            A0 = ea + (size_t)r0.y * 8;
        }
        float4 a00 = *(const float4*)A0;
        float4 a01 = *(const float4*)(A0 + 4);
        const float* K0 = K + (size_t)s0 * HCP + h * CP;
        const float* V0 = V + (size_t)s0 * HCP + h * CP;
        float k0[CP], v0[CP];
#pragma unroll
        for (int t4 = 0; t4 < CP / 4; ++t4) {
            *(float4*)(k0 + 4 * t4) = *(const float4*)(K0 + 4 * t4);
            *(float4*)(v0 + 4 * t4) = *(const float4*)(V0 + 4 * t4);
        }
        float d0 = 0.f;
#pragma unroll
        for (int c = 0; c < C; ++c) d0 = fmaf(q[c], k0[c], d0);
        float qa0 = qe[0] * a00.x;
        qa0 = fmaf(qe[1], a00.y, qa0); qa0 = fmaf(qe[2], a00.z, qa0);
        qa0 = fmaf(qe[3], a00.w, qa0); qa0 = fmaf(qe[4], a01.x, qa0);
        qa0 = fmaf(qe[5], a01.y, qa0); qa0 = fmaf(qe[6], a01.z, qa0);
        qa0 = fmaf(qe[7], a01.w, qa0);
        float ex0 = __expf((d0 + qa0) * scale);
        den += ex0;
#pragma unroll
        for (int c = 0; c < C; ++c) num[c] = fmaf(ex0, v0[c], num[c]);
        sacc[0] = fmaf(ex0, a00.x, sacc[0]);
        sacc[1] = fmaf(ex0, a00.y, sacc[1]);
        sacc[2] = fmaf(ex0, a00.z, sacc[2]);
        sacc[3] = fmaf(ex0, a00.w, sacc[3]);
        sacc[4] = fmaf(ex0, a01.x, sacc[4]);
        sacc[5] = fmaf(ex0, a01.y, sacc[5]);
        sacc[6] = fmaf(ex0, a01.z, sacc[6]);
        sacc[7] = fmaf(ex0, a01.w, sacc[7]);
    }

    float inv = 1.f / (den + 1e-16f);
    float outc[C], sc[C];
    float gd = 0.f;
#pragma unroll
    for (int c = 0; c < C; ++c) {
        float e_ = 0.f;
#pragma unroll
        for (int d = 0; d < 8; ++d) e_ = fmaf(we[d * HC + h * C + c], sacc[d], e_);
        float o = (num[c] + e_) * inv;
        float s_ = S[(size_t)n * HC + h * C + c];
        outc[c] = o;
        sc[c] = s_;
        gd += o * wb[h * C + c] + s_ * wb[HC + h * C + c] + (o - s_) * wb[2 * HC + h * C + c];
    }
    gd += __shfl_xor(gd, 1, 8);
    gd += __shfl_xor(gd, 2, 8);
    gd += __shfl_xor(gd, 4, 8);
    float g = 1.f / (1.f + __expf(-gd));
#pragma unroll
    for (int c = 0; c < C; ++c) {
        float hh = fmaxf(g * sc[c] + (1.f - g) * outc[c], 0.f);
        OUT[(size_t)n * HC + h * C + c] = hh;
    }
}

// ---- fused gather+gate+classifier, H=1,C=64: 16 lanes/node, factorized ----
template<bool PERM>
__global__ void gather64f_kernel(const int* __restrict__ rowptr,
                                 const int* __restrict__ srcp,
                                 const int2* __restrict__ rec,
                                 const float* __restrict__ eap,
                                 const float* __restrict__ ea,
                                 const float* __restrict__ we,
                                 const float* __restrict__ Q,
                                 const float* __restrict__ K,
                                 const float* __restrict__ V,
                                 const float* __restrict__ S,
                                 const float* __restrict__ wb,
                                 const float* __restrict__ wc,
                                 const float* __restrict__ bc,
                                 float* __restrict__ OUT,
                                 int N, float scale)
{
    int grp = (blockIdx.x * blockDim.x + threadIdx.x) >> 4;   // node
    int l16 = threadIdx.x & 15;
    if (grp >= N) return;
    int c0 = l16 << 2;

    float wv[8][4];
#pragma unroll
    for (int d = 0; d < 8; ++d) *(float4*)wv[d] = *(const float4*)(we + d * 64 + c0);
    float4 qv = *(const float4*)(Q + (size_t)grp * 64 + c0);
    // per-lane partial qe[d] = sum over this lane's 4 channels of we[d][c]*q[c]
    float qe[8];
#pragma unroll
    for (int d = 0; d < 8; ++d) {
        float t = wv[d][0] * qv.x;
        t = fmaf(wv[d][1], qv.y, t);
        t = fmaf(wv[d][2], qv.z, t);
        t = fmaf(wv[d][3], qv.w, t);
        qe[d] = t;
    }

    float num0 = 0.f, num1 = 0.f, num2 = 0.f, num3 = 0.f, den = 0.f;
    float sacc[8];
#pragma unroll
    for (int d = 0; d < 8; ++d) sacc[d] = 0.f;

    int rs = rowptr[grp], re = rowptr[grp + 1];
    int j = rs;
    for (; j + 1 < re; j += 2) {
        int s0, s1;
        const float *A0, *A1;
        if (PERM) {
            s0 = srcp[j]; s1 = srcp[j + 1];
            A0 = eap + (size_t)j * 8; A1 = eap + (size_t)(j + 1) * 8;
        } else {
            int2 r0 = rec[j], r1 = rec[j + 1];
            s0 = r0.x; s1 = r1.x;
            A0 = ea + (size_t)r0.y * 8; A1 = ea + (size_t)r1.y * 8;
        }
        float4 a00 = *(const float4*)A0;
        float4 a01 = *(const float4*)(A0 + 4);
        float4 a10 = *(const float4*)A1;
        float4 a11 = *(const float4*)(A1 + 4);
        float4 k0 = *(const float4*)(K + (size_t)s0 * 64 + c0);
        float4 v0 = *(const float4*)(V + (size_t)s0 * 64 + c0);
        float4 k1 = *(const float4*)(K + (size_t)s1 * 64 + c0);
        float4 v1 = *(const float4*)(V + (size_t)s1 * 64 + c0);
        // partial logit: q.k + q.e (via per-lane qe partials)
        float t0 = qv.x * k0.x;
        t0 = fmaf(qv.y, k0.y, t0); t0 = fmaf(qv.z, k0.z, t0); t0 = fmaf(qv.w, k0.w, t0);
        t0 = fmaf(qe[0], a00.x, t0); t0 = fmaf(qe[1], a00.y, t0);
        t0 = fmaf(qe[2], a00.z, t0); t0 = fmaf(qe[3], a00.w, t0);
        t0 = fmaf(qe[4], a01.x, t0); t0 = fmaf(qe[5], a01.y, t0);
        t0 = fmaf(qe[6], a01.z, t0); t0 = fmaf(qe[7], a01.w, t0);
        float t1 = qv.x * k1.x;
        t1 = fmaf(qv.y, k1.y, t1); t1 = fmaf(qv.z, k1.z, t1); t1 = fmaf(qv.w, k1.w, t1);
        t1 = fmaf(qe[0], a10.x, t1); t1 = fmaf(qe[1], a10.y, t1);
        t1 = fmaf(qe[2], a10.z, t1); t1 = fmaf(qe[3], a10.w, t1);
        t1 = fmaf(qe[4], a11.x, t1); t1 = fmaf(qe[5], a11.y, t1);
        t1 = fmaf(qe[6], a11.z, t1); t1 = fmaf(qe[7], a11.w, t1);
#pragma unroll
        for (int off = 8; off > 0; off >>= 1) {
            t0 += __shfl_xor(t0, off, 16);
            t1 += __shfl_xor(t1, off, 16);
        }
        float ex0 = __expf(t0 * scale);
        float ex1 = __expf(t1 * scale);
        den += ex0 + ex1;
        num0 = fmaf(ex0, v0.x, fmaf(ex1, v1.x, num0));
        num1 = fmaf(ex0, v0.y, fmaf(ex1, v1.y, num1));
        num2 = fmaf(ex0, v0.z, fmaf(ex1, v1.z, num2));
        num3 = fmaf(ex0, v0.w, fmaf(ex1, v1.w, num3));
        sacc[0] = fmaf(ex0, a00.x, fmaf(ex1, a10.x, sacc[0]));
        sacc[1] = fmaf(ex0, a00.y, fmaf(ex1, a10.y, sacc[1]));
        sacc[2] = fmaf(ex0, a00.z, fmaf(ex1, a10.z, sacc[2]));
        sacc[3] = fmaf(ex0, a00.w, fmaf(ex1, a10.w, sacc[3]));
        sacc[4] = fmaf(ex0, a01.x, fmaf(ex1, a11.x, sacc[4]));
        sacc[5] = fmaf(ex0, a01.y, fmaf(ex1, a11.y, sacc[5]));
        sacc[6] = fmaf(ex0, a01.z, fmaf(ex1, a11.z, sacc[6]));
        sacc[7] = fmaf(ex0, a01.w, fmaf(ex1, a11.w, sacc[7]));
    }
    if (j < re) {
        int s0;
        const float* A0;
        if (PERM) {
            s0 = srcp[j];
            A0 = eap + (size_t)j * 8;
        } else {
            int2 r0 = rec[j];
            s0 = r0.x;
            A0 = ea + (size_t)r0.y * 8;
        }
        float4 a00 = *(const float4*)A0;
        float4 a01 = *(const float4*)(A0 + 4);
        float4 k0 = *(const float4*)(K + (size_t)s0 * 64 + c0);
        float4 v0 = *(const float4*)(V + (size_t)s0 * 64 + c0);
        float t0 = qv.x * k0.x;
        t0 = fmaf(qv.y, k0.y, t0); t0 = fmaf(qv.z, k0.z, t0); t0 = fmaf(qv.w, k0.w, t0);
        t0 = fmaf(qe[0], a00.x, t0); t0 = fmaf(qe[1], a00.y, t0);
        t0 = fmaf(qe[2], a00.z, t0); t0 = fmaf(qe[3], a00.w, t0);
        t0 = fmaf(qe[4], a01.x, t0); t0 = fmaf(qe[5], a01.y, t0);
        t0 = fmaf(qe[6], a01.z, t0); t0 = fmaf(qe[7], a01.w, t0);
#pragma unroll
        for (int off = 8; off > 0; off >>= 1) t0 += __shfl_xor(t0, off, 16);
        float ex0 = __expf(t0 * scale);
        den += ex0;
        num0 = fmaf(ex0, v0.x, num0);
        num1 = fmaf(ex0, v0.y, num1);
        num2 = fmaf(ex0, v0.z, num2);
        num3 = fmaf(ex0, v0.w, num3);
        sacc[0] = fmaf(ex0, a00.x, sacc[0]);
        sacc[1] = fmaf(ex0, a00.y, sacc[1]);
        sacc[2] = fmaf(ex0, a00.z, sacc[2]);
        sacc[3] = fmaf(ex0, a00.w, sacc[3]);
        sacc[4] = fmaf(ex0, a01.x, sacc[4]);
        sacc[5] = fmaf(ex0, a01.y, sacc[5]);
        sacc[6] = fmaf(ex0, a01.z, sacc[6]);
        sacc[7] = fmaf(ex0, a01.w, sacc[7]);
    }

    // num correction: num_c += sum_d we[d][c] * sacc[d]  (sacc lane-uniform)
#pragma unroll
    for (int d = 0; d < 8; ++d) {
        num0 = fmaf(wv[d][0], sacc[d], num0);
        num1 = fmaf(wv[d][1], sacc[d], num1);
        num2 = fmaf(wv[d][2], sacc[d], num2);
        num3 = fmaf(wv[d][3], sacc[d], num3);
    }
    float inv = 1.f / (den + 1e-16f);
    float o0 = num0 * inv, o1 = num1 * inv, o2 = num2 * inv, o3 = num3 * inv;
    float4 sv  = *(const float4*)(S + (size_t)grp * 64 + c0);
    float4 wb0 = *(const float4*)(wb + c0);
    float4 wb1 = *(const float4*)(wb + 64 + c0);
    float4 wb2 = *(const float4*)(wb + 128 + c0);
    float gd = o0 * wb0.x + sv.x * wb1.x + (o0 - sv.x) * wb2.x;
    gd += o1 * wb0.y + sv.y * wb1.y + (o1 - sv.y) * wb2.y;
    gd += o2 * wb0.z + sv.z * wb1.z + (o2 - sv.z) * wb2.z;
    gd += o3 * wb0.w + sv.w * wb1.w + (o3 - sv.w) * wb2.w;
#pragma unroll
    for (int off = 8; off > 0; off >>= 1) gd += __shfl_xor(gd, off, 16);
    float g = 1.f / (1.f + __expf(-gd));
    float h0 = fmaxf(g * sv.x + (1.f - g) * o0, 0.f);
    float h1 = fmaxf(g * sv.y + (1.f - g) * o1, 0.f);
    float h2 = fmaxf(g * sv.z + (1.f - g) * o2, 0.f);
    float h3 = fmaxf(g * sv.w + (1.f - g) * o3, 0.f);
    float4 wcv = *(const float4*)(wc + c0);
    float t = h0 * wcv.x + h1 * wcv.y + h2 * wcv.z + h3 * wcv.w;
#pragma unroll
    for (int off = 8; off > 0; off >>= 1) t += __shfl_xor(t, off, 16);
    if (l16 == 0) OUT[grp] = t + bc[0];
}

extern "C" void kernel_launch(void* const* d_in, const int* in_sizes, int n_in,
                              void* d_out, int out_size, void* d_ws, size_t ws_size,
                              hipStream_t stream) {
    const float* x  = (const float*)d_in[0];
    const int*   ei = (const int*)d_in[1];
    const float* ea = (const float*)d_in[2];
    const int N = in_sizes[0] / 32;
    const int E = in_sizes[1] / 2;

    int p = 3;
    const float *wq1=(const float*)d_in[p+0], *bq1=(const float*)d_in[p+1],
                *wk1=(const float*)d_in[p+2], *bk1=(const float*)d_in[p+3],
                *wv1=(const float*)d_in[p+4], *bv1=(const float*)d_in[p+5],
                *we1=(const float*)d_in[p+6],
                *wsk1=(const float*)d_in[p+7], *bsk1=(const float*)d_in[p+8],
                *wb1=(const float*)d_in[p+9];
    p += 10;
    const float *wq2=(const float*)d_in[p+0], *bq2=(const float*)d_in[p+1],
                *wk2=(const float*)d_in[p+2], *bk2=(const float*)d_in[p+3],
                *wv2=(const float*)d_in[p+4], *bv2=(const float*)d_in[p+5],
                *we2=(const float*)d_in[p+6],
                *wsk2=(const float*)d_in[p+7], *bsk2=(const float*)d_in[p+8],
                *wb2=(const float*)d_in[p+9];
    p += 10;
    const float *wq3=(const float*)d_in[p+0], *bq3=(const float*)d_in[p+1],
                *wk3=(const float*)d_in[p+2], *bk3=(const float*)d_in[p+3],
                *wv3=(const float*)d_in[p+4], *bv3=(const float*)d_in[p+5],
                *we3=(const float*)d_in[p+6],
                *wsk3=(const float*)d_in[p+7], *bsk3=(const float*)d_in[p+8],
                *wb3=(const float*)d_in[p+9];
    p += 10;
    const float *wc = (const float*)d_in[p+0], *bc = (const float*)d_in[p+1];

    float* out = (float*)d_out;

    // ---- workspace layout ----
    size_t NB = (size_t)N * 64;
    float* ws = (float*)d_ws;
    float* Hb = ws;              // N*48 (max hidden between layers)
    float* Qb = Hb + (size_t)N * 48;
    float* Kb = Qb + NB;
    float* Vb = Kb + NB;
    float* Sb = Vb + NB;
    int* ip      = (int*)(Sb + NB);
    int* rowptr  = ip;                 // N+2
    int* deg     = rowptr + (N + 2);   // N (cursor)
    int* bsum    = deg + N;            // 512
    int* boff    = bsum + 512;         // 512
    int* idx_end = boff + 512;

    // PERM layout: srcp[E] then 16B-aligned eap[E*8]
    int* srcp = idx_end;
    size_t eap_off = (size_t)((char*)(srcp + E) - (char*)d_ws);
    eap_off = (eap_off + 15) & ~(size_t)15;
    float* eap = (float*)((char*)d_ws + eap_off);
    size_t need_perm = eap_off + (size_t)E * 8 * sizeof(float);

    // fallback layout: rec[E] (int2)
    size_t rec_off = (size_t)((char*)idx_end - (char*)d_ws);
    rec_off = (rec_off + 7) & ~(size_t)7;
    int2* rec = (int2*)((char*)d_ws + rec_off);

    const bool PERM = (ws_size >= need_perm);

    const int BLK = 256;
    const int NBLK = (N + SCAN_BLK - 1) / SCAN_BLK;

    // ---------------- CSR build ----------------
    hipMemsetAsync(deg, 0, (size_t)N * sizeof(int), stream);
    count_kernel<<<(E + BLK - 1) / BLK, BLK, 0, stream>>>(ei, deg, E);
    scan1_kernel<<<NBLK, SCAN_BLK, 0, stream>>>(deg, rowptr, bsum, N);
    scan2_kernel<<<1, 512, 0, stream>>>(bsum, boff, NBLK);
    scan3_kernel<<<(N + BLK - 1) / BLK, BLK, 0, stream>>>(rowptr, boff, N, E);
    hipMemsetAsync(deg, 0, (size_t)N * sizeof(int), stream);
    if (PERM)
        scatterP_kernel<<<(E + BLK - 1) / BLK, BLK, 0, stream>>>(ei, rowptr, deg, srcp, eap, ea, E);
    else
        scatterR_kernel<<<(E + BLK - 1) / BLK, BLK, 0, stream>>>(ei, rowptr, deg, rec, E);

    // ------- layer 1: cin=32, H=8, C=6 (pad 8) -------
    proj_kernel<32,8,6,8><<<(N*48 + BLK-1)/BLK, BLK, 0, stream>>>(
        x, wq1,bq1, wk1,bk1, wv1,bv1, wsk1,bsk1, Qb,Kb,Vb,Sb, N);
    if (PERM)
        gather8f_kernel<6,8,true><<<(N*8 + BLK-1)/BLK, BLK, 0, stream>>>(
            rowptr, srcp, rec, eap, ea, we1, Qb, Kb, Vb, Sb, wb1, Hb, N, 1.0f/sqrtf(6.0f));
    else
        gather8f_kernel<6,8,false><<<(N*8 + BLK-1)/BLK, BLK, 0, stream>>>(
            rowptr, srcp, rec, eap, ea, we1, Qb, Kb, Vb, Sb, wb1, Hb, N, 1.0f/sqrtf(6.0f));

    // ------- layer 2: cin=48, H=8, C=3 (pad 4) -------
    proj_kernel<48,8,3,4><<<(N*24 + BLK-1)/BLK, BLK, 0, stream>>>(
        Hb, wq2,bq2, wk2,bk2, wv2,bv2, wsk2,bsk2, Qb,Kb,Vb,Sb, N);
    if (PERM)
        gather8f_kernel<3,4,true><<<(N*8 + BLK-1)/BLK, BLK, 0, stream>>>(
            rowptr, srcp, rec, eap, ea, we2, Qb, Kb, Vb, Sb, wb2, Hb, N, 1.0f/sqrtf(3.0f));
    else
        gather8f_kernel<3,4,false><<<(N*8 + BLK-1)/BLK, BLK, 0, stream>>>(
            rowptr, srcp, rec, eap, ea, we2, Qb, Kb, Vb, Sb, wb2, Hb, N, 1.0f/sqrtf(3.0f));

    // ------- layer 3: cin=24, H=1, C=64 -------
    proj_kernel<24,1,64,64><<<(N*64 + BLK-1)/BLK, BLK, 0, stream>>>(
        Hb, wq3,bq3, wk3,bk3, wv3,bv3, wsk3,bsk3, Qb,Kb,Vb,Sb, N);
    if (PERM)
        gather64f_kernel<true><<<((size_t)N*16 + BLK-1)/BLK, BLK, 0, stream>>>(
            rowptr, srcp, rec, eap, ea, we3, Qb, Kb, Vb, Sb, wb3, wc, bc, out, N, 1.0f/8.0f);
    else
        gather64f_kernel<false><<<((size_t)N*16 + BLK-1)/BLK, BLK, 0, stream>>>(
            rowptr, srcp, rec, eap, ea, we3, Qb, Kb, Vb, Sb, wb3, wc, bc, out, N, 1.0f/8.0f);
}